// Round 9
// baseline (111.048 us; speedup 1.0000x reference)
//
#include <hip/hip_runtime.h>
#include <hip/hip_fp16.h>
#include <hip/hip_cooperative_groups.h>

namespace cg = cooperative_groups;

#define NB 16384     // batch rows
#define ND 256       // d_in (GEMM K)
#define NH 1024      // hidden (GEMM N)
#define NK 16        // sparse fan-in

using f16x8 = __attribute__((ext_vector_type(8))) _Float16;
using f32x4 = __attribute__((ext_vector_type(4))) float;

#define C2LOG2E 2.8853900817779268f   // 2*log2(e): tanh(y)=1-2/(2^(y*C2)+1)

__device__ __forceinline__ void scat8(float (&a)[8], int ii, float ww, int d0) {
#pragma unroll
    for (int e = 0; e < 8; ++e)
        if (ii == d0 + e) a[e] += ww;
}

// one MFMA half-chunk: 4 k-slices x 4 row-tiles, compile-time indices only
#define MFMA_HALF(ACC, BFR, KOFF)                                             \
    _Pragma("unroll")                                                         \
    for (int ks = 0; ks < 4; ++ks) {                                          \
        _Pragma("unroll")                                                     \
        for (int mi = 0; mi < 4; ++mi)                                        \
            ACC[mi] = __builtin_amdgcn_mfma_f32_16x16x32_f16(                 \
                af[mi][(KOFF) + ks], BFR[ks], ACC[mi], 0, 0, 0);              \
    }

#define ZERO_ACC(ACC)                                                         \
    _Pragma("unroll")                                                         \
    for (int mi = 0; mi < 4; ++mi) ACC[mi] = f32x4{0.f, 0.f, 0.f, 0.f};

// ---------------------------------------------------------------------------
// Single cooperative kernel.
// Phase A: all threads issue their x loads (HBM latency starts); threads
//   0..127 scatter 4 h-rows of w1 into fragment-ordered Wf (f16).
// grid.sync()  (Wf produced by all 256 blocks, consumed by all)
// Phase B: stage x tile -> swizzled LDS f16; pull af[4][8] (AGPR-resident);
//   main loop over 8 rotated n-chunks with PING-PONG acc: chunk nc's MFMAs
//   overlap chunk nc-1's tanh epilogue (removes the acc-chain stall).
//   Final shfl + LDS reduce, tanh, store. No atomics.
// ---------------------------------------------------------------------------
__global__ __launch_bounds__(512, 2) void fused_coop_kernel(
        const float* __restrict__ x, const int* __restrict__ idx,
        const float* __restrict__ w1, const float* __restrict__ b1,
        const float* __restrict__ w2, const float* __restrict__ b2,
        _Float16* __restrict__ Wf, float* __restrict__ out) {
    __shared__ _Float16 lA[64 * 256];   // 32 KB, 16B chunks swizzled: c ^= (r&7)
    __shared__ float red[8 * 64];       // 2 KB cross-wave reduction

    const int t = threadIdx.x;
    const int lane = t & 63;
    const int w = t >> 6;               // wave 0..7
    const int gm0 = blockIdx.x * 64;
    const int ml = lane & 15;
    const int kg = lane >> 4;
    const int start = ((blockIdx.x >> 3) + w) & 7;   // chunk rotation

    // ================= PHASE A =================
    // issue x loads first (HBM latency hides under the build work)
    const int sr  = t >> 3;             // 0..63 staging row
    const int sub = t & 7;              // 32 f32 each
    const float4* xsrc = reinterpret_cast<const float4*>(
        x + (size_t)(gm0 + sr) * ND + sub * 32);
    float4 v[8];
#pragma unroll
    for (int j = 0; j < 8; ++j) v[j] = xsrc[j];

    // distributed Wf build: 4 h-rows per block, threads 0..127
    if (t < 128) {
        int h  = blockIdx.x * 4 + (t >> 5);
        int g  = t & 31;
        int d0 = g << 3;
        const int4*   ip = reinterpret_cast<const int4*>(idx + h * NK);
        const float4* wp = reinterpret_cast<const float4*>(w1 + h * NK);
        float a[8];
#pragma unroll
        for (int e = 0; e < 8; ++e) a[e] = 0.f;
#pragma unroll
        for (int j = 0; j < 4; ++j) {
            int4   I = ip[j];
            float4 V = wp[j];
            scat8(a, I.x, V.x, d0);
            scat8(a, I.y, V.y, d0);
            scat8(a, I.z, V.z, d0);
            scat8(a, I.w, V.w, d0);
        }
        int c  = h >> 4;
        int mh = h & 15;
        int ks = g >> 2;
        int k4 = g & 3;
        size_t off = (((size_t)(c * 8 + ks)) * 64 + k4 * 16 + mh) * 8;
        f16x8 o;
#pragma unroll
        for (int e = 0; e < 8; ++e) o[e] = (_Float16)a[e];
        *reinterpret_cast<f16x8*>(&Wf[off]) = o;
    }
    __threadfence();                    // Wf visible device-wide
    cg::this_grid().sync();

    // ================= PHASE B =================
    // chunk-0/1 B loads (L2-resident Wf)
    const _Float16* gW = Wf + (size_t)w * 32768 + (size_t)lane * 8;
    f16x8 bA[4], bB[4];
    {
        const _Float16* p0 = gW + start * 4096;
#pragma unroll
        for (int ks = 0; ks < 4; ++ks)
            bA[ks] = *reinterpret_cast<const f16x8*>(p0 + ks * 512);
#pragma unroll
        for (int ks = 0; ks < 4; ++ks)
            bB[ks] = *reinterpret_cast<const f16x8*>(p0 + 2048 + ks * 512);
    }

    // stage x tile (64x256) -> LDS f16, swizzled
#pragma unroll
    for (int q = 0; q < 4; ++q) {
        int c = sub * 4 + q;
        f16x8 hh;
        hh[0] = (_Float16)v[2*q].x;   hh[1] = (_Float16)v[2*q].y;
        hh[2] = (_Float16)v[2*q].z;   hh[3] = (_Float16)v[2*q].w;
        hh[4] = (_Float16)v[2*q+1].x; hh[5] = (_Float16)v[2*q+1].y;
        hh[6] = (_Float16)v[2*q+1].z; hh[7] = (_Float16)v[2*q+1].w;
        int a16 = sr * 32 + (c ^ (sr & 7));
        *reinterpret_cast<f16x8*>(&lA[a16 * 8]) = hh;
    }
    __syncthreads();

    // pull this wave's A fragments into registers (AGPR-resident, whole loop)
    f16x8 af[4][8];
#pragma unroll
    for (int mi = 0; mi < 4; ++mi)
#pragma unroll
        for (int ks = 0; ks < 8; ++ks) {
            int r = mi * 16 + ml;
            int c = ks * 4 + kg;
            af[mi][ks] = *reinterpret_cast<const f16x8*>(
                &lA[(r * 32 + (c ^ (r & 7))) * 8]);
        }

    float rowpart[4][4];
#pragma unroll
    for (int mi = 0; mi < 4; ++mi)
#pragma unroll
        for (int r4 = 0; r4 < 4; ++r4) rowpart[mi][r4] = 0.f;

    // epilogue: rowpart += tanh(acc + b1) * w2, trimmed to 4 VALU + 2 trans
    auto EPI = [&](const f32x4 (&A)[4], float b1v, float w2v) {
        float b1c = b1v * C2LOG2E;
#pragma unroll
        for (int mi = 0; mi < 4; ++mi)
#pragma unroll
            for (int r4 = 0; r4 < 4; ++r4) {
                float arg = __builtin_fmaf(A[mi][r4], C2LOG2E, b1c);
                float e = __builtin_exp2f(arg);
                float r = __builtin_amdgcn_rcpf(e + 1.0f);
                float th = __builtin_fmaf(-2.f, r, 1.f);
                rowpart[mi][r4] = __builtin_fmaf(th, w2v, rowpart[mi][r4]);
            }
    };

    const int colbase = w * 128 + ml;
    f32x4 accE[4], accO[4];
    float b1E = 0.f, w2E = 0.f, b1O = 0.f, w2O = 0.f;

    // main loop: 4 pairs of chunks; acc ping-pong so chunk nc's epilogue
    // runs under chunk nc+1's MFMAs
#pragma unroll 1
    for (int p = 0; p < 4; ++p) {
        // ---- even chunk nc = 2p -> accE ----
        {
            const int ncc = (start + 2 * p) & 7;
            b1E = b1[colbase + ncc * 16];
            w2E = w2[colbase + ncc * 16];
            ZERO_ACC(accE);
            const _Float16* pn = gW + (((start + 2 * p + 1) & 7) * 4096);

            __builtin_amdgcn_s_setprio(1);
            MFMA_HALF(accE, bA, 0);
            __builtin_amdgcn_s_setprio(0);
#pragma unroll
            for (int ks = 0; ks < 4; ++ks)
                bA[ks] = *reinterpret_cast<const f16x8*>(pn + ks * 512);

            __builtin_amdgcn_s_setprio(1);
            MFMA_HALF(accE, bB, 4);
            __builtin_amdgcn_s_setprio(0);
#pragma unroll
            for (int ks = 0; ks < 4; ++ks)
                bB[ks] = *reinterpret_cast<const f16x8*>(pn + 2048 + ks * 512);

            if (p > 0) EPI(accO, b1O, w2O);   // prev odd chunk's epilogue
        }
        // ---- odd chunk nc = 2p+1 -> accO ----
        {
            const int ncc = (start + 2 * p + 1) & 7;
            b1O = b1[colbase + ncc * 16];
            w2O = w2[colbase + ncc * 16];
            ZERO_ACC(accO);
            const _Float16* pn = gW + (((start + 2 * p + 2) & 7) * 4096);

            __builtin_amdgcn_s_setprio(1);
            MFMA_HALF(accO, bA, 0);
            __builtin_amdgcn_s_setprio(0);
            if (p < 3) {
#pragma unroll
                for (int ks = 0; ks < 4; ++ks)
                    bA[ks] = *reinterpret_cast<const f16x8*>(pn + ks * 512);
            }

            __builtin_amdgcn_s_setprio(1);
            MFMA_HALF(accO, bB, 4);
            __builtin_amdgcn_s_setprio(0);
            if (p < 3) {
#pragma unroll
                for (int ks = 0; ks < 4; ++ks)
                    bB[ks] = *reinterpret_cast<const f16x8*>(pn + 2048 + ks * 512);
            }

            EPI(accE, b1E, w2E);              // this pair's even chunk
        }
    }
    EPI(accO, b1O, w2O);                      // final odd chunk (nc=7)

    // ---- reduce over the 16 col-lanes of each group ----
#pragma unroll
    for (int mi = 0; mi < 4; ++mi)
#pragma unroll
        for (int r4 = 0; r4 < 4; ++r4) {
            float vv = rowpart[mi][r4];
            vv += __shfl_xor(vv, 1);
            vv += __shfl_xor(vv, 2);
            vv += __shfl_xor(vv, 4);
            vv += __shfl_xor(vv, 8);
            rowpart[mi][r4] = vv;
        }
    if (ml == 0) {
#pragma unroll
        for (int mi = 0; mi < 4; ++mi)
#pragma unroll
            for (int r4 = 0; r4 < 4; ++r4)
                red[w * 64 + mi * 16 + kg * 4 + r4] = rowpart[mi][r4];
    }
    __syncthreads();

    // ---- cross-wave sum + final tanh + store ----
    if (t < 64) {
        float s = 0.f;
#pragma unroll
        for (int j = 0; j < 8; ++j) s += red[j * 64 + t];
        float arg = __builtin_fmaf(s, C2LOG2E, b2[0] * C2LOG2E);
        float e = __builtin_exp2f(arg);
        out[gm0 + t] = 1.0f - 2.0f * __builtin_amdgcn_rcpf(e + 1.0f);
    }
}

extern "C" void kernel_launch(void* const* d_in, const int* in_sizes, int n_in,
                              void* d_out, int out_size, void* d_ws, size_t ws_size,
                              hipStream_t stream) {
    const float* x   = (const float*)d_in[0];
    const int*   idx = (const int*)d_in[1];
    const float* w1  = (const float*)d_in[2];
    const float* b1  = (const float*)d_in[3];
    const float* w2  = (const float*)d_in[4];
    const float* b2  = (const float*)d_in[5];
    float* out = (float*)d_out;
    _Float16* Wf = (_Float16*)d_ws;     // 512 KB fragment-ordered W

    void* args[] = { (void*)&x, (void*)&idx, (void*)&w1, (void*)&b1,
                     (void*)&w2, (void*)&b2, (void*)&Wf, (void*)&out };
    hipLaunchCooperativeKernel((const void*)fused_coop_kernel,
                               dim3(NB / 64), dim3(512), args, 0, stream);
}

// Round 10
// 23.819 us; speedup vs baseline: 4.6621x; 4.6621x over previous
//
#include <hip/hip_runtime.h>
#include <hip/hip_fp16.h>

#define NB 16384     // batch rows
#define ND 256       // d_in (GEMM K)
#define NH 1024      // hidden (GEMM N)
#define NK 16        // sparse fan-in

using f16x8 = __attribute__((ext_vector_type(8))) _Float16;
using f32x4 = __attribute__((ext_vector_type(4))) float;

#define C2LOG2E 2.8853900817779268f   // 2*log2(e): tanh(y)=1-2/(2^(y*C2)+1)

__device__ __forceinline__ void scat8(float (&a)[8], int ii, float ww, int d0) {
#pragma unroll
    for (int e = 0; e < 8; ++e)
        if (ii == d0 + e) a[e] += ww;
}

#define MFMA_HALF(ACC, BFR, KOFF)                                             \
    _Pragma("unroll")                                                         \
    for (int ks = 0; ks < 4; ++ks) {                                          \
        _Pragma("unroll")                                                     \
        for (int mi = 0; mi < 4; ++mi)                                        \
            ACC[mi] = __builtin_amdgcn_mfma_f32_16x16x32_f16(                 \
                af[mi][(KOFF) + ks], BFR[ks], ACC[mi], 0, 0, 0);              \
    }

#define ZERO_ACC(ACC)                                                         \
    _Pragma("unroll")                                                         \
    for (int mi = 0; mi < 4; ++mi) ACC[mi] = f32x4{0.f, 0.f, 0.f, 0.f};

// ---------------------------------------------------------------------------
// Kernel 1: scatter w1 into FRAGMENT-ORDERED dense Wf (f16). (frozen, R5)
// ---------------------------------------------------------------------------
__global__ __launch_bounds__(128) void build_w_kernel(
        const int* __restrict__ idx, const float* __restrict__ w1,
        _Float16* __restrict__ Wf) {
    int t = blockIdx.x * 128 + threadIdx.x;
    int h = t >> 5;
    int g = t & 31;
    int d0 = g << 3;
    const int4*   ip = reinterpret_cast<const int4*>(idx + h * NK);
    const float4* wp = reinterpret_cast<const float4*>(w1 + h * NK);
    float a[8];
#pragma unroll
    for (int e = 0; e < 8; ++e) a[e] = 0.f;
#pragma unroll
    for (int j = 0; j < 4; ++j) {
        int4   I = ip[j];
        float4 V = wp[j];
        scat8(a, I.x, V.x, d0);
        scat8(a, I.y, V.y, d0);
        scat8(a, I.z, V.z, d0);
        scat8(a, I.w, V.w, d0);
    }
    int c  = h >> 4;
    int ml = h & 15;
    int ks = g >> 2;
    int kg = g & 3;
    size_t off = (((size_t)(c * 8 + ks)) * 64 + kg * 16 + ml) * 8;
    f16x8 o;
#pragma unroll
    for (int e = 0; e < 8; ++e) o[e] = (_Float16)a[e];
    *reinterpret_cast<f16x8*>(&Wf[off]) = o;
}

// ---------------------------------------------------------------------------
// Kernel 2: fused GEMM+MLP, R5 structure + PING-PONG accumulators:
// chunk nc's tanh-epilogue (VALU+trans) executes under chunk nc+1's MFMAs
// (independent acc registers), removing the acc-chain serialization that
// R7/R8 counters exposed (MfmaUtil 34 / VALUBusy 51 / ~50% dual-idle).
// Epilogue trimmed to 4 VALU + 2 trans per element via exp2.
// ---------------------------------------------------------------------------
__global__ __launch_bounds__(512, 2) void fused_kernel(
        const float* __restrict__ x, const _Float16* __restrict__ Wf,
        const float* __restrict__ b1, const float* __restrict__ w2,
        const float* __restrict__ b2, float* __restrict__ out) {
    __shared__ _Float16 lA[64 * 256];   // 32 KB, swizzled 16B chunks: c ^= (r&7)
    __shared__ float red[8 * 64];       // 2 KB cross-wave reduction

    const int t = threadIdx.x;
    const int lane = t & 63;
    const int w = t >> 6;               // wave 0..7
    const int gm0 = blockIdx.x * 64;
    const int ml = lane & 15;
    const int kg = lane >> 4;
    const int start = ((blockIdx.x >> 3) + w) & 7;   // chunk rotation

    // ---- issue x loads first (HBM), then start-chunk B loads (L2) ----
    const int sr  = t >> 3;
    const int sub = t & 7;
    const float4* xsrc = reinterpret_cast<const float4*>(
        x + (size_t)(gm0 + sr) * ND + sub * 32);
    float4 v[8];
#pragma unroll
    for (int j = 0; j < 8; ++j) v[j] = xsrc[j];

    const _Float16* gW = Wf + (size_t)w * 32768 + (size_t)lane * 8;
    f16x8 bA[4], bB[4];
    {
        const _Float16* p0 = gW + start * 4096;
#pragma unroll
        for (int ks = 0; ks < 4; ++ks)
            bA[ks] = *reinterpret_cast<const f16x8*>(p0 + ks * 512);
#pragma unroll
        for (int ks = 0; ks < 4; ++ks)
            bB[ks] = *reinterpret_cast<const f16x8*>(p0 + 2048 + ks * 512);
    }

    // ---- stage x tile (64x256) -> LDS f16, swizzled ----
#pragma unroll
    for (int q = 0; q < 4; ++q) {
        int c = sub * 4 + q;
        f16x8 hh;
        hh[0] = (_Float16)v[2*q].x;   hh[1] = (_Float16)v[2*q].y;
        hh[2] = (_Float16)v[2*q].z;   hh[3] = (_Float16)v[2*q].w;
        hh[4] = (_Float16)v[2*q+1].x; hh[5] = (_Float16)v[2*q+1].y;
        hh[6] = (_Float16)v[2*q+1].z; hh[7] = (_Float16)v[2*q+1].w;
        int a16 = sr * 32 + (c ^ (sr & 7));
        *reinterpret_cast<f16x8*>(&lA[a16 * 8]) = hh;
    }
    __syncthreads();

    // ---- pull this wave's A fragments into registers (whole kernel) ----
    f16x8 af[4][8];
#pragma unroll
    for (int mi = 0; mi < 4; ++mi)
#pragma unroll
        for (int ks = 0; ks < 8; ++ks) {
            int r = mi * 16 + ml;
            int c = ks * 4 + kg;
            af[mi][ks] = *reinterpret_cast<const f16x8*>(
                &lA[(r * 32 + (c ^ (r & 7))) * 8]);
        }

    float rowpart[4][4];
#pragma unroll
    for (int mi = 0; mi < 4; ++mi)
#pragma unroll
        for (int r4 = 0; r4 < 4; ++r4) rowpart[mi][r4] = 0.f;

    // epilogue: rowpart += tanh(acc + b1) * w2  (4 VALU + 2 trans / elem)
    auto EPI = [&](const f32x4 (&A)[4], float b1v, float w2v) {
        float b1c = b1v * C2LOG2E;
#pragma unroll
        for (int mi = 0; mi < 4; ++mi)
#pragma unroll
            for (int r4 = 0; r4 < 4; ++r4) {
                float arg = __builtin_fmaf(A[mi][r4], C2LOG2E, b1c);
                float e = __builtin_exp2f(arg);
                float r = __builtin_amdgcn_rcpf(e + 1.0f);
                float th = __builtin_fmaf(-2.f, r, 1.f);
                rowpart[mi][r4] = __builtin_fmaf(th, w2v, rowpart[mi][r4]);
            }
    };

    const int colbase = w * 128 + ml;
    f32x4 accE[4], accO[4];
    float b1E = 0.f, w2E = 0.f, b1O = 0.f, w2O = 0.f;

    // ---- main loop: 4 chunk-pairs, ping-pong acc ----
#pragma unroll 1
    for (int p = 0; p < 4; ++p) {
        // even chunk nc = 2p -> accE
        {
            const int ncc = (start + 2 * p) & 7;
            b1E = b1[colbase + ncc * 16];
            w2E = w2[colbase + ncc * 16];
            ZERO_ACC(accE);
            const _Float16* pn = gW + (((start + 2 * p + 1) & 7) * 4096);

            __builtin_amdgcn_s_setprio(1);
            MFMA_HALF(accE, bA, 0);
            __builtin_amdgcn_s_setprio(0);
#pragma unroll
            for (int ks = 0; ks < 4; ++ks)
                bA[ks] = *reinterpret_cast<const f16x8*>(pn + ks * 512);

            __builtin_amdgcn_s_setprio(1);
            MFMA_HALF(accE, bB, 4);
            __builtin_amdgcn_s_setprio(0);
#pragma unroll
            for (int ks = 0; ks < 4; ++ks)
                bB[ks] = *reinterpret_cast<const f16x8*>(pn + 2048 + ks * 512);

            if (p > 0) EPI(accO, b1O, w2O);   // prev odd chunk under these MFMAs
        }
        // odd chunk nc = 2p+1 -> accO
        {
            const int ncc = (start + 2 * p + 1) & 7;
            b1O = b1[colbase + ncc * 16];
            w2O = w2[colbase + ncc * 16];
            ZERO_ACC(accO);
            const _Float16* pn = gW + (((start + 2 * p + 2) & 7) * 4096);

            __builtin_amdgcn_s_setprio(1);
            MFMA_HALF(accO, bA, 0);
            __builtin_amdgcn_s_setprio(0);
            if (p < 3) {
#pragma unroll
                for (int ks = 0; ks < 4; ++ks)
                    bA[ks] = *reinterpret_cast<const f16x8*>(pn + ks * 512);
            }

            __builtin_amdgcn_s_setprio(1);
            MFMA_HALF(accO, bB, 4);
            __builtin_amdgcn_s_setprio(0);
            if (p < 3) {
#pragma unroll
                for (int ks = 0; ks < 4; ++ks)
                    bB[ks] = *reinterpret_cast<const f16x8*>(pn + 2048 + ks * 512);
            }

            EPI(accE, b1E, w2E);              // this pair's even chunk
        }
    }
    EPI(accO, b1O, w2O);                      // final odd chunk (nc = start+7)

    // ---- reduce over the 16 col-lanes of each group ----
#pragma unroll
    for (int mi = 0; mi < 4; ++mi)
#pragma unroll
        for (int r4 = 0; r4 < 4; ++r4) {
            float vv = rowpart[mi][r4];
            vv += __shfl_xor(vv, 1);
            vv += __shfl_xor(vv, 2);
            vv += __shfl_xor(vv, 4);
            vv += __shfl_xor(vv, 8);
            rowpart[mi][r4] = vv;
        }
    if (ml == 0) {
#pragma unroll
        for (int mi = 0; mi < 4; ++mi)
#pragma unroll
            for (int r4 = 0; r4 < 4; ++r4)
                red[w * 64 + mi * 16 + kg * 4 + r4] = rowpart[mi][r4];
    }
    __syncthreads();

    // ---- cross-wave sum + final tanh + store ----
    if (t < 64) {
        float s = 0.f;
#pragma unroll
        for (int j = 0; j < 8; ++j) s += red[j * 64 + t];
        float arg = __builtin_fmaf(s, C2LOG2E, b2[0] * C2LOG2E);
        float e = __builtin_exp2f(arg);
        out[gm0 + t] = 1.0f - 2.0f * __builtin_amdgcn_rcpf(e + 1.0f);
    }
}

extern "C" void kernel_launch(void* const* d_in, const int* in_sizes, int n_in,
                              void* d_out, int out_size, void* d_ws, size_t ws_size,
                              hipStream_t stream) {
    const float* x   = (const float*)d_in[0];
    const int*   idx = (const int*)d_in[1];
    const float* w1  = (const float*)d_in[2];
    const float* b1  = (const float*)d_in[3];
    const float* w2  = (const float*)d_in[4];
    const float* b2  = (const float*)d_in[5];
    float* out = (float*)d_out;

    _Float16* Wf = (_Float16*)d_ws;     // 512 KB fragment-ordered W

    build_w_kernel<<<(NH * 32) / 128, 128, 0, stream>>>(idx, w1, Wf);
    fused_kernel<<<NB / 64, 512, 0, stream>>>(x, Wf, b1, w2, b2, out);
}